// Round 23
// baseline (218.718 us; speedup 1.0000x reference)
//
#include <hip/hip_runtime.h>

#define N_NODES 102
#define NP 8192          // pairs (B*n)
#define NROWS 835584     // NP * N_NODES
#define RBLOCKS 3264     // 256-row blocks
#define RSTRIDE 128      // persistent grid x-dim

typedef _Float16 f16x8 __attribute__((ext_vector_type(8)));
typedef _Float16 f16x2 __attribute__((ext_vector_type(2)));
typedef float f32x4 __attribute__((ext_vector_type(4)));

// ---------------- Kernel 1: build sparse propagation tables ----------------------
__global__ void build_tables(const int* __restrict__ ei, int ne,
                             int4* __restrict__ gtu, float4* __restrict__ gtw) {
    __shared__ int   deg[N_NODES];
    __shared__ float dinv[N_NODES];
    __shared__ int   cnt[N_NODES];
    __shared__ int   tu[N_NODES][4];
    __shared__ float tw[N_NODES][4];
    int t = threadIdx.x;
    if (t < N_NODES) deg[t] = 1;                       // self-loop
    __syncthreads();
    if (t == 0) for (int e = 0; e < ne; ++e) deg[ei[ne + e]] += 1;
    __syncthreads();
    if (t < N_NODES) {
        dinv[t] = 1.0f / sqrtf((float)deg[t]);
        cnt[t] = 1;
        for (int j = 0; j < 4; ++j) { tu[t][j] = 2 * t; tw[t][j] = 0.0f; }
    }
    __syncthreads();
    if (t < N_NODES) tw[t][0] = dinv[t] * dinv[t];     // diagonal self-loop
    __syncthreads();
    if (t == 0) {
        for (int e = 0; e < ne; ++e) {
            int r = ei[e], c = ei[ne + e];
            int s = cnt[c] < 4 ? cnt[c] : 3;           // clamp (never hit here)
            cnt[c] = s + 1;
            tu[c][s] = 2 * r;
            tw[c][s] = dinv[r] * dinv[c];
        }
    }
    __syncthreads();
    if (t < N_NODES) {
        gtu[t] = make_int4(tu[t][0], tu[t][1], tu[t][2], tu[t][3]);
        gtw[t] = make_float4(tw[t][0], tw[t][1], tw[t][2], tw[t][3]);
    }
}

// ---------------- Kernel 1b: WpT[col][k] = (f16)Wp[k][col] (proven in R13) -------
__global__ void prep_w(const float* __restrict__ Wp, _Float16* __restrict__ WpT) {
    int tid = blockIdx.x * 256 + threadIdx.x;          // 64 x 256 = 16384
    for (int i = tid; i < 65536; i += 16384) {         // i = k*256 + col (coalesced)
        int col = i & 255, k = i >> 8;
        WpT[col * 256 + k] = (_Float16)Wp[i];
    }
}

// ---------------- Kernel 1c: y[r] = sparse-propagated x (one thread per row) -----
// Tables (102 entries) and x-slices (816B/pair) are L1/L2-resident; y stores
// coalesced 8B/lane. Moves the scatter-gather OUT of the HBM-bound main kernel.
__global__ void compute_y(const float* __restrict__ x,
                          const int4* __restrict__ gtu,
                          const float4* __restrict__ gtw,
                          float2* __restrict__ y) {
    int r = blockIdx.x * 256 + threadIdx.x;            // < NROWS (grid exact)
    int p = r / N_NODES;                               // magic-mul
    int v = r - p * N_NODES;
    int4  U = gtu[v];
    float4 W = gtw[v];
    const float* xp = x + (size_t)p * (2 * N_NODES);
    float a0 = W.x * xp[U.x]     + W.y * xp[U.y]
             + W.z * xp[U.z]     + W.w * xp[U.w];
    float a1 = W.x * xp[U.x + 1] + W.y * xp[U.y + 1]
             + W.z * xp[U.z + 1] + W.w * xp[U.w + 1];
    y[r] = make_float2(a0, a1);
}

// ---------------- Kernel 2: persistent GNN, barrier-free, reg-prefetched y -------
// R15 core with y PRECOMPUTED: no xs LDS, no tables, no in-loop barriers, no
// gathers. Per iter: 4 broadcast-coalesced float2 y-loads double-buffered in
// NAMED registers (2-body unroll), issued before the epilogue stores so the
// compiler's wait retires only them. LDS in-loop = 24 conflict-free W reads.
#define GNN_BODY(YC, YN, ROWBLK, PREF_OK, PREF_RB)                                   \
    {                                                                                \
        const int rowblk_ = (ROWBLK);                                                \
        f16x2 y0pk[4], y1pk[4];                                                      \
        _Pragma("unroll")                                                            \
        for (int s = 0; s < 4; ++s) {                                                \
            _Float16 h0 = (_Float16)YC[s].x;                                         \
            _Float16 h1 = (_Float16)YC[s].y;                                         \
            y0pk[s] = (f16x2){ h0, h0 };                                             \
            y1pk[s] = (f16x2){ h1, h1 };                                             \
        }                                                                            \
        if (PREF_OK) {                                                               \
            const long rbase_ = (long)(PREF_RB) * 256 + w * 64 + m;                  \
            _Pragma("unroll")                                                        \
            for (int s = 0; s < 4; ++s) YN[s] = yg[rbase_ + s * 16];                 \
        }                                                                            \
        f32x4 acc[4][4];                                                             \
        _Pragma("unroll")                                                            \
        for (int s = 0; s < 4; ++s)                                                  \
            _Pragma("unroll")                                                        \
            for (int nt = 0; nt < 4; ++nt) acc[s][nt] = (f32x4){0.f,0.f,0.f,0.f};    \
        _Pragma("unroll")                                                            \
        for (int t = 0; t < 8; ++t) {                                                \
            const int kk = qk * 8 + 32 * t;                                          \
            union { f16x8 v; f16x2 p[4]; } w0u, w1u, bbu;                            \
            w0u.v = *reinterpret_cast<const f16x8*>(&W0l[kk]);                       \
            w1u.v = *reinterpret_cast<const f16x8*>(&W1l[kk]);                       \
            bbu.v = *reinterpret_cast<const f16x8*>(&bgl[kk]);                       \
            _Pragma("unroll")                                                        \
            for (int s = 0; s < 4; ++s) {                                            \
                union { f16x8 v; f16x2 p[4]; } af;                                   \
                _Pragma("unroll")                                                    \
                for (int j2 = 0; j2 < 4; ++j2) {                                     \
                    f16x2 h = w0u.p[j2] * y0pk[s] + w1u.p[j2] * y1pk[s] + bbu.p[j2]; \
                    af.p[j2] = __builtin_elementwise_max(h, z2);                     \
                }                                                                    \
                _Pragma("unroll")                                                    \
                for (int nt = 0; nt < 4; ++nt)                                       \
                    acc[s][nt] = __builtin_amdgcn_mfma_f32_16x16x32_f16(             \
                        af.v, bfragR[t][nt], acc[s][nt], 0, 0, 0);                   \
            }                                                                        \
        }                                                                            \
        const long rowbase_ = (long)rowblk_ + (long)w * 64;                          \
        _Pragma("unroll")                                                            \
        for (int s = 0; s < 4; ++s) {                                                \
            _Pragma("unroll")                                                        \
            for (int nt = 0; nt < 4; ++nt) {                                         \
                const int e = c0 + nt * 16 + m;                                      \
                _Pragma("unroll")                                                    \
                for (int reg = 0; reg < 4; ++reg) {                                  \
                    long r = rowbase_ + s * 16 + qk * 4 + reg;                       \
                    out[r * 256 + e] = acc[s][nt][reg] + bpf[nt];                    \
                }                                                                    \
            }                                                                        \
        }                                                                            \
    }

__global__ __launch_bounds__(256, 2) void gnn_main(
    const float2* __restrict__ yg,     // [NROWS] precomputed y
    const _Float16* __restrict__ WpT,  // [256 col][256 k] f16
    const float* __restrict__ Wg,      // [2][256]
    const float* __restrict__ bg,      // [256]
    const float* __restrict__ bp,      // [256]
    float* __restrict__ out)           // [NROWS][256]
{
    __shared__ _Float16 W0l[256], W1l[256], bgl[256];
    const int tid = threadIdx.x;
    const int w  = tid >> 6;
    const int l  = tid & 63;
    const int qk = l >> 4;
    const int m  = l & 15;
    const int c0  = blockIdx.y * 64;
    const int rbi = blockIdx.x;

    // Hoist all B fragments into registers (32 x 16B, L2-resident WpT)
    f16x8 bfragR[8][4];
    #pragma unroll
    for (int t = 0; t < 8; ++t)
        #pragma unroll
        for (int nt = 0; nt < 4; ++nt)
            bfragR[t][nt] = *reinterpret_cast<const f16x8*>(
                &WpT[(c0 + nt * 16 + m) * 256 + qk * 8 + 32 * t]);

    // Stage GNN weights (once)
    W0l[tid] = (_Float16)Wg[tid];
    W1l[tid] = (_Float16)Wg[256 + tid];
    bgl[tid] = (_Float16)bg[tid];

    float bpf[4];
    #pragma unroll
    for (int nt = 0; nt < 4; ++nt) bpf[nt] = bp[c0 + nt * 16 + m];

    // Prologue: load y for iteration 0
    float2 yA[4], yB[4];
    {
        const long rbase = (long)rbi * 256 + w * 64 + m;
        #pragma unroll
        for (int s = 0; s < 4; ++s) yA[s] = yg[rbase + s * 16];
    }
    __syncthreads();   // W0l/W1l/bgl staged (single full drain)

    const f16x2 z2 = (f16x2){ (_Float16)0.0f, (_Float16)0.0f };

    #pragma unroll 1
    for (int jj = 0; jj < 13; ++jj) {
        const int jA = 2 * jj, jB = 2 * jj + 1;
        const int rbA = rbi + jA * RSTRIDE;            // always < RBLOCKS
        const int rbB = rbi + jB * RSTRIDE;
        const int rbN = rbi + (jA + 2) * RSTRIDE;      // next body-A rowblock

        // Body A: compute rbA from yA, prefetch yB for rbB
        GNN_BODY(yA, yB, rbA * 256, (rbB < RBLOCKS), rbB)

        // Body B: compute rbB from yB, prefetch yA for rbN
        if (rbB < RBLOCKS) {
            GNN_BODY(yB, yA, rbB * 256, (rbN < RBLOCKS), rbN)
        }
    }
}

extern "C" void kernel_launch(void* const* d_in, const int* in_sizes, int n_in,
                              void* d_out, int out_size, void* d_ws, size_t ws_size,
                              hipStream_t stream) {
    const float* x  = (const float*)d_in[0];
    const float* Wg = (const float*)d_in[1];
    const float* bg = (const float*)d_in[2];
    const float* Wp = (const float*)d_in[3];
    const float* bp = (const float*)d_in[4];
    const int* ei   = (const int*)d_in[5];
    float* out = (float*)d_out;

    const int ne = in_sizes[5] / 2;                 // 84

    int4*     gtu = (int4*)d_ws;                        // 102 int4
    float4*   gtw = (float4*)((char*)d_ws + 2048);      // 102 float4
    _Float16* WpT = (_Float16*)((char*)d_ws + 4096);    // 65536 f16 = 128 KB
    float2*   yws = (float2*)((char*)d_ws + 4096 + 131072);  // NROWS float2 = 6.7 MB

    build_tables<<<1, 128, 0, stream>>>(ei, ne, gtu, gtw);
    prep_w<<<64, 256, 0, stream>>>(Wp, WpT);
    compute_y<<<NROWS / 256, 256, 0, stream>>>(x, gtu, gtw, yws);

    gnn_main<<<dim3(RSTRIDE, 4), 256, 0, stream>>>(yws, WpT, Wg, bg, bp, out);
}